// Round 1
// baseline (249.327 us; speedup 1.0000x reference)
//
#include <hip/hip_runtime.h>
#include <math.h>

// Router: x[4,4096,2048] f32, W[64,2048] f32
// out (all f32, concatenated): topk_weight[16384,2], topk_idx[16384,2] (as float), aux_loss[1]

#define D_MODEL     2048
#define NUM_EXPERTS 64
#define N_ROWS      16384
#define ALPHA       0.01f

#define BR      32      // rows per block
#define BK      32      // k-chunk
#define THREADS 256

#define SX 36           // lds x row stride (floats): 16B-aligned rows, conflict-free reads
#define SW 68           // lds W^T row stride (floats)
#define SL 72           // lds logits row stride (floats)

__global__ __launch_bounds__(THREADS)
void router_fused(const float* __restrict__ x, const float* __restrict__ W,
                  float* __restrict__ out_w, float* __restrict__ out_i,
                  float* __restrict__ g_pi, float* __restrict__ g_cnt) {
    __shared__ float lx[BR * SX];            // x chunk   [row][k]
    __shared__ float lw[BK * SW];            // W^T chunk [k][expert]
    __shared__ float ll[BR * SL];            // logits    [row][expert]
    __shared__ float apx[4][NUM_EXPERTS];    // per-wave partial Pi sums
    __shared__ float acn[4][NUM_EXPERTS];    // per-wave partial counts

    const int tid = threadIdx.x;
    const int rb  = blockIdx.x * BR;

    // ---- staging map: thread -> (row 0..31, 4-k segment) ----
    const int srow = tid >> 3;            // 0..31
    const int skb  = (tid & 7) * 4;       // 0,4,...,28

    const float* xg  = x + (size_t)(rb + srow) * D_MODEL + skb;
    const float* wg0 = W + (size_t)srow        * D_MODEL + skb;   // experts 0..31
    const float* wg1 = W + (size_t)(srow + 32) * D_MODEL + skb;   // experts 32..63

    // ---- compute map: thread -> (2 rows, 4 experts) ----
    const int tx = tid & 15;              // 0..15 -> experts tx*4..tx*4+3
    const int ty = tid >> 4;              // 0..15 -> rows ty*2, ty*2+1
    const int r0 = ty * 2, r1 = ty * 2 + 1;
    const int eb = tx * 4;

    float acc[2][4] = {{0.f,0.f,0.f,0.f},{0.f,0.f,0.f,0.f}};

    // prologue prefetch: chunk 0
    float4 px  = *(const float4*)(xg);
    float4 pw0 = *(const float4*)(wg0);
    float4 pw1 = *(const float4*)(wg1);

    for (int kc = 0; kc < D_MODEL / BK; ++kc) {
        __syncthreads();   // previous compute done; safe to overwrite LDS
        // write staged regs to LDS (W transposed: lw[k][e])
        *(float4*)&lx[srow * SX + skb] = px;
        lw[(skb + 0) * SW + srow] = pw0.x;
        lw[(skb + 1) * SW + srow] = pw0.y;
        lw[(skb + 2) * SW + srow] = pw0.z;
        lw[(skb + 3) * SW + srow] = pw0.w;
        lw[(skb + 0) * SW + srow + 32] = pw1.x;
        lw[(skb + 1) * SW + srow + 32] = pw1.y;
        lw[(skb + 2) * SW + srow + 32] = pw1.z;
        lw[(skb + 3) * SW + srow + 32] = pw1.w;
        // issue next chunk's global loads early (hide HBM under compute)
        if (kc + 1 < D_MODEL / BK) {
            const int o = (kc + 1) * BK;
            px  = *(const float4*)(xg  + o);
            pw0 = *(const float4*)(wg0 + o);
            pw1 = *(const float4*)(wg1 + o);
        }
        __syncthreads();   // LDS ready

        #pragma unroll
        for (int kk = 0; kk < BK / 4; ++kk) {
            const float4 xa = *(const float4*)&lx[r0 * SX + kk * 4];
            const float4 xb = *(const float4*)&lx[r1 * SX + kk * 4];
            const float4 w0 = *(const float4*)&lw[(kk * 4 + 0) * SW + eb];
            const float4 w1 = *(const float4*)&lw[(kk * 4 + 1) * SW + eb];
            const float4 w2 = *(const float4*)&lw[(kk * 4 + 2) * SW + eb];
            const float4 w3 = *(const float4*)&lw[(kk * 4 + 3) * SW + eb];

            acc[0][0] += xa.x*w0.x + xa.y*w1.x + xa.z*w2.x + xa.w*w3.x;
            acc[0][1] += xa.x*w0.y + xa.y*w1.y + xa.z*w2.y + xa.w*w3.y;
            acc[0][2] += xa.x*w0.z + xa.y*w1.z + xa.z*w2.z + xa.w*w3.z;
            acc[0][3] += xa.x*w0.w + xa.y*w1.w + xa.z*w2.w + xa.w*w3.w;

            acc[1][0] += xb.x*w0.x + xb.y*w1.x + xb.z*w2.x + xb.w*w3.x;
            acc[1][1] += xb.x*w0.y + xb.y*w1.y + xb.z*w2.y + xb.w*w3.y;
            acc[1][2] += xb.x*w0.z + xb.y*w1.z + xb.z*w2.z + xb.w*w3.z;
            acc[1][3] += xb.x*w0.w + xb.y*w1.w + xb.z*w2.w + xb.w*w3.w;
        }
    }

    // ---- logits to LDS ----
    *(float4*)&ll[r0 * SL + eb] = make_float4(acc[0][0], acc[0][1], acc[0][2], acc[0][3]);
    *(float4*)&ll[r1 * SL + eb] = make_float4(acc[1][0], acc[1][1], acc[1][2], acc[1][3]);
    __syncthreads();

    // ---- softmax + top2, wave-per-row-group: wave w handles rows w*8..w*8+7 ----
    const int wv   = tid >> 6;   // 0..3
    const int lane = tid & 63;   // = expert
    float pi_acc  = 0.f;
    float cnt_acc = 0.f;

    for (int r8 = 0; r8 < 8; ++r8) {
        const int row = wv * 8 + r8;
        const float lg = ll[row * SL + lane];

        // wave max
        float m = lg;
        #pragma unroll
        for (int off = 32; off; off >>= 1) m = fmaxf(m, __shfl_xor(m, off));
        const float e = expf(lg - m);
        float s = e;
        #pragma unroll
        for (int off = 32; off; off >>= 1) s += __shfl_xor(s, off);
        const float score = e / s;

        // top-1 (ties -> lower index, matching lax.top_k)
        float v1 = score; int i1 = lane;
        #pragma unroll
        for (int off = 32; off; off >>= 1) {
            const float ov = __shfl_xor(v1, off);
            const int   oi = __shfl_xor(i1, off);
            if (ov > v1 || (ov == v1 && oi < i1)) { v1 = ov; i1 = oi; }
        }
        // top-2: mask out winner
        float v2 = (lane == i1) ? -1.f : score; int i2 = lane;
        #pragma unroll
        for (int off = 32; off; off >>= 1) {
            const float ov = __shfl_xor(v2, off);
            const int   oi = __shfl_xor(i2, off);
            if (ov > v2 || (ov == v2 && oi < i2)) { v2 = ov; i2 = oi; }
        }

        if (lane == 0) {
            const int grow = rb + row;
            const float denom = v1 + v2 + 1e-9f;
            out_w[grow * 2 + 0] = v1 / denom;
            out_w[grow * 2 + 1] = v2 / denom;
            out_i[grow * 2 + 0] = (float)i1;
            out_i[grow * 2 + 1] = (float)i2;
        }

        pi_acc  += score;
        cnt_acc += (float)((lane == i1) + (lane == i2));
    }

    apx[wv][lane] = pi_acc;
    acn[wv][lane] = cnt_acc;
    __syncthreads();

    if (tid < NUM_EXPERTS) {
        const float p = apx[0][tid] + apx[1][tid] + apx[2][tid] + apx[3][tid];
        const float c = acn[0][tid] + acn[1][tid] + acn[2][tid] + acn[3][tid];
        atomicAdd(&g_pi[tid],  p);
        atomicAdd(&g_cnt[tid], c);
    }
}

__global__ void router_finalize(const float* __restrict__ g_pi,
                                const float* __restrict__ g_cnt,
                                float* __restrict__ aux_out) {
    const int lane = threadIdx.x;  // 64 threads
    const float pi = g_pi[lane] * (1.0f / (float)N_ROWS);            // Pi[e]
    const float fi = g_cnt[lane] * (64.0f / (float)(N_ROWS * 2));    // freq*E
    float v = pi * fi;
    #pragma unroll
    for (int off = 32; off; off >>= 1) v += __shfl_xor(v, off);
    if (lane == 0) aux_out[0] = v * ALPHA;
}

extern "C" void kernel_launch(void* const* d_in, const int* in_sizes, int n_in,
                              void* d_out, int out_size, void* d_ws, size_t ws_size,
                              hipStream_t stream) {
    const float* x = (const float*)d_in[0];
    const float* W = (const float*)d_in[1];

    float* out   = (float*)d_out;
    float* out_w = out;                   // [N,2] weights
    float* out_i = out + N_ROWS * 2;      // [N,2] indices (as float)
    float* aux   = out + N_ROWS * 4;      // [1]

    float* g_pi  = (float*)d_ws;          // [64] score sums
    float* g_cnt = g_pi + NUM_EXPERTS;    // [64] counts

    hipMemsetAsync(d_ws, 0, 2 * NUM_EXPERTS * sizeof(float), stream);

    router_fused<<<dim3(N_ROWS / BR), dim3(THREADS), 0, stream>>>(
        x, W, out_w, out_i, g_pi, g_cnt);
    router_finalize<<<dim3(1), dim3(64), 0, stream>>>(g_pi, g_cnt, aux);
}

// Round 2
// 248.762 us; speedup vs baseline: 1.0023x; 1.0023x over previous
//
#include <hip/hip_runtime.h>
#include <math.h>

// Router: x[4,4096,2048] f32, W[64,2048] f32
// out f32 concat: topk_weight[16384,2], topk_idx[16384,2] (as float), aux_loss[1]
//
// Split-K design:
//   k1 router_gemm: grid (64 row-blocks x 8 k-slices), 256 thr, 8x8 reg tile/thread
//      -> partial[8][16384][64] in ws (32 MB)
//   k2 router_softmax: reduce slices + softmax + top2 + aux accumulation
//   k3 router_finalize: aux loss scalar

#define D_MODEL     2048
#define NUM_EXPERTS 64
#define N_ROWS      16384
#define ALPHA       0.01f

#define SLICES  8
#define KSLICE  (D_MODEL / SLICES)    // 256
#define BK      16
#define CHUNKS  (KSLICE / BK)         // 16
#define BR      256                   // rows per block
#define THREADS 256

__global__ __launch_bounds__(THREADS, 2)
void router_gemm(const float* __restrict__ x, const float* __restrict__ W,
                 float* __restrict__ partial) {
    // lx: [row][k-quad] 16B slots, quad-XOR-swizzled, linear for global_load_lds
    __shared__ float lx[2][BR * BK];          // 16 KB each
    __shared__ float lw[2][BK * NUM_EXPERTS]; // 4 KB each, [k][expert]

    const int tid  = threadIdx.x;
    const int lane = tid & 63;
    const int wv   = tid >> 6;     // wave 0..3
    const int tx   = tid & 7;      // expert-group: experts tx*4.. and 32+tx*4..
    const int ty   = tid >> 3;     // 0..31: rows ty, ty+32, ..., ty+224
    const int rb   = blockIdx.x * BR;
    const int kbase = blockIdx.y * KSLICE;
    const int sw   = (ty >> 1) & 3;   // x read-swizzle for this thread's rows

    float4 a0[8], a1[8];
    #pragma unroll
    for (int i = 0; i < 8; ++i) {
        a0[i] = make_float4(0.f, 0.f, 0.f, 0.f);
        a1[i] = make_float4(0.f, 0.f, 0.f, 0.f);
    }

    const int we = lane;   // expert this thread stages
    const int wq = wv;     // k-quad this thread stages

    #define STAGE(buf, t)                                                          \
    {                                                                              \
        const int k0 = kbase + (t) * BK;                                           \
        _Pragma("unroll")                                                          \
        for (int n = 0; n < 4; ++n) {                                              \
            const int base_slot = (wv * 4 + n) * 64;                               \
            const int S  = base_slot + lane;                                       \
            const int R  = S >> 2;                                                 \
            const int c  = S & 3;                                                  \
            const int qs = c ^ (((R & 31) >> 1) & 3);                              \
            const float* gp = x + (size_t)(rb + R) * D_MODEL + k0 + qs * 4;        \
            __builtin_amdgcn_global_load_lds(                                      \
                (const __attribute__((address_space(1))) void*)gp,                 \
                (__attribute__((address_space(3))) void*)&lx[buf][base_slot * 4],  \
                16, 0, 0);                                                         \
        }                                                                          \
        const float4 wval = *(const float4*)(W + (size_t)we * D_MODEL + k0 + wq * 4); \
        lw[buf][(wq * 4 + 0) * 64 + we] = wval.x;                                  \
        lw[buf][(wq * 4 + 1) * 64 + we] = wval.y;                                  \
        lw[buf][(wq * 4 + 2) * 64 + we] = wval.z;                                  \
        lw[buf][(wq * 4 + 3) * 64 + we] = wval.w;                                  \
    }

    #define COMPUTE(buf)                                                           \
    {                                                                              \
        _Pragma("unroll")                                                          \
        for (int q = 0; q < 4; ++q) {                                              \
            float4 xr[8];                                                          \
            const int cq = (q ^ sw) * 4;                                           \
            _Pragma("unroll")                                                      \
            for (int i = 0; i < 8; ++i)                                            \
                xr[i] = *(const float4*)&lx[buf][(ty + i * 32) * BK + cq];         \
            _Pragma("unroll")                                                      \
            for (int j = 0; j < 4; ++j) {                                          \
                const int k = q * 4 + j;                                           \
                const float4 wa = *(const float4*)&lw[buf][k * 64 + tx * 4];       \
                const float4 wb = *(const float4*)&lw[buf][k * 64 + 32 + tx * 4];  \
                _Pragma("unroll")                                                  \
                for (int i = 0; i < 8; ++i) {                                      \
                    const float xv = (j == 0) ? xr[i].x : (j == 1) ? xr[i].y       \
                                   : (j == 2) ? xr[i].z : xr[i].w;                 \
                    a0[i].x += xv * wa.x; a0[i].y += xv * wa.y;                    \
                    a0[i].z += xv * wa.z; a0[i].w += xv * wa.w;                    \
                    a1[i].x += xv * wb.x; a1[i].y += xv * wb.y;                    \
                    a1[i].z += xv * wb.z; a1[i].w += xv * wb.w;                    \
                }                                                                  \
            }                                                                      \
        }                                                                          \
    }

    STAGE(0, 0)
    int buf = 0;
    for (int t = 0; t < CHUNKS; ++t) {
        __syncthreads();
        if (t + 1 < CHUNKS) STAGE(buf ^ 1, t + 1)
        COMPUTE(buf)
        buf ^= 1;
    }

    const size_t srow = (size_t)blockIdx.y * N_ROWS + rb;
    #pragma unroll
    for (int i = 0; i < 8; ++i) {
        float* p = partial + (srow + ty + i * 32) * NUM_EXPERTS;
        *(float4*)(p + tx * 4)      = a0[i];
        *(float4*)(p + 32 + tx * 4) = a1[i];
    }
    #undef STAGE
    #undef COMPUTE
}

__global__ __launch_bounds__(256)
void router_softmax(const float* __restrict__ partial,
                    float* __restrict__ out_w, float* __restrict__ out_i,
                    float* __restrict__ g_pi, float* __restrict__ g_cnt) {
    __shared__ float apx[4][NUM_EXPERTS];
    __shared__ float acn[4][NUM_EXPERTS];

    const int tid  = threadIdx.x;
    const int lane = tid & 63;     // = expert
    const int wv   = tid >> 6;
    const int wave_id = blockIdx.x * 4 + wv;   // 0..2047

    float pi_acc = 0.f, cnt_acc = 0.f;

    for (int rr = 0; rr < 8; ++rr) {
        const int row = wave_id * 8 + rr;

        float lg = 0.f;
        #pragma unroll
        for (int s = 0; s < SLICES; ++s)
            lg += partial[((size_t)s * N_ROWS + row) * NUM_EXPERTS + lane];

        // softmax over 64 experts (lane = expert)
        float m = lg;
        #pragma unroll
        for (int off = 32; off; off >>= 1) m = fmaxf(m, __shfl_xor(m, off));
        const float e = expf(lg - m);
        float s = e;
        #pragma unroll
        for (int off = 32; off; off >>= 1) s += __shfl_xor(s, off);
        const float score = e / s;

        // top-1 (ties -> lower index, matching lax.top_k)
        float v1 = score; int i1 = lane;
        #pragma unroll
        for (int off = 32; off; off >>= 1) {
            const float ov = __shfl_xor(v1, off);
            const int   oi = __shfl_xor(i1, off);
            if (ov > v1 || (ov == v1 && oi < i1)) { v1 = ov; i1 = oi; }
        }
        // top-2
        float v2 = (lane == i1) ? -1.f : score; int i2 = lane;
        #pragma unroll
        for (int off = 32; off; off >>= 1) {
            const float ov = __shfl_xor(v2, off);
            const int   oi = __shfl_xor(i2, off);
            if (ov > v2 || (ov == v2 && oi < i2)) { v2 = ov; i2 = oi; }
        }

        if (lane == 0) {
            const float denom = v1 + v2 + 1e-9f;
            out_w[row * 2 + 0] = v1 / denom;
            out_w[row * 2 + 1] = v2 / denom;
            out_i[row * 2 + 0] = (float)i1;
            out_i[row * 2 + 1] = (float)i2;
        }

        pi_acc  += score;
        cnt_acc += (float)((lane == i1) + (lane == i2));
    }

    apx[wv][lane] = pi_acc;
    acn[wv][lane] = cnt_acc;
    __syncthreads();

    if (tid < NUM_EXPERTS) {
        const float p = apx[0][tid] + apx[1][tid] + apx[2][tid] + apx[3][tid];
        const float c = acn[0][tid] + acn[1][tid] + acn[2][tid] + acn[3][tid];
        atomicAdd(&g_pi[tid],  p);
        atomicAdd(&g_cnt[tid], c);
    }
}

__global__ void router_finalize(const float* __restrict__ g_pi,
                                const float* __restrict__ g_cnt,
                                float* __restrict__ aux_out) {
    const int lane = threadIdx.x;  // 64 threads
    const float pi = g_pi[lane] * (1.0f / (float)N_ROWS);
    const float fi = g_cnt[lane] * (64.0f / (float)(N_ROWS * 2));
    float v = pi * fi;
    #pragma unroll
    for (int off = 32; off; off >>= 1) v += __shfl_xor(v, off);
    if (lane == 0) aux_out[0] = v * ALPHA;
}

extern "C" void kernel_launch(void* const* d_in, const int* in_sizes, int n_in,
                              void* d_out, int out_size, void* d_ws, size_t ws_size,
                              hipStream_t stream) {
    const float* x = (const float*)d_in[0];
    const float* W = (const float*)d_in[1];

    float* out   = (float*)d_out;
    float* out_w = out;                   // [N,2]
    float* out_i = out + N_ROWS * 2;      // [N,2] as float
    float* aux   = out + N_ROWS * 4;      // [1]

    float* g_pi    = (float*)d_ws;            // [64]
    float* g_cnt   = g_pi + NUM_EXPERTS;      // [64]
    float* partial = (float*)d_ws + 256;      // [SLICES][N_ROWS][64] = 32 MB

    hipMemsetAsync(d_ws, 0, 512, stream);

    router_gemm<<<dim3(N_ROWS / BR, SLICES), dim3(THREADS), 0, stream>>>(x, W, partial);
    router_softmax<<<dim3(N_ROWS / 32), dim3(256), 0, stream>>>(partial, out_w, out_i, g_pi, g_cnt);
    router_finalize<<<dim3(1), dim3(64), 0, stream>>>(g_pi, g_cnt, aux);
}

// Round 5
// 218.348 us; speedup vs baseline: 1.1419x; 1.1393x over previous
//
#include <hip/hip_runtime.h>
#include <math.h>
#include <stdint.h>

// Router: x[4,4096,2048] f32, W[64,2048] f32
// out f32 concat: topk_weight[16384,2], topk_idx[16384,2] (as float), aux_loss[1]
//
// f16-split MFMA design:
//   k0 w_prep: W -> packed (hi|lo<<16) f16 image, XOR-swizzled for linear global_load_lds
//   k1 router_mfma: fused GEMM (16x16x32 f16 MFMA, 3-term split) + softmax + top2 + aux
//   k2 router_finalize: aux scalar
// Scaling: x*256, W*1024 (exact pow2), logits /2^18 in epilogue (exact).

#define D_MODEL 2048
#define NE      64
#define N_ROWS  16384
#define ALPHA   0.01f
#define BR      32
#define BK      64
#define NCH     (D_MODEL / BK)   // 32
#define THREADS 512

typedef _Float16 f16x8 __attribute__((ext_vector_type(8)));
typedef float    f32x4 __attribute__((ext_vector_type(4)));

union U4 { uint32_t u[4]; uint4 v; };
union F8 { uint32_t u[4]; f16x8 v; };

__device__ __forceinline__ uint32_t pack_hl(float xs) {
    _Float16 h = (_Float16)xs;
    float hf = (float)h;
    _Float16 l = (_Float16)(xs - hf);
    union { _Float16 f; uint16_t b; } ch, cl;
    ch.f = h; cl.f = l;
    return (uint32_t)ch.b | ((uint32_t)cl.b << 16);
}

#define GLD16(src, dst) __builtin_amdgcn_global_load_lds( \
    (const __attribute__((address_space(1))) void*)(src), \
    (__attribute__((address_space(3))) void*)(dst), 16, 0, 0)

// ---- k0: convert W once to packed-swizzled image ----
// Element W[e][k] (uint u) lives at img[c*4096 + (e*16 + ((kl>>2) ^ (e&7)))*4 + (kl&3)]
// with c = k>>6, kl = k&63.  16B slot = 4 consecutive k.
__global__ __launch_bounds__(256)
void w_prep(const float* __restrict__ W, uint32_t* __restrict__ img) {
    const int idx = blockIdx.x * 256 + threadIdx.x;   // 0..131071
    const int e = idx >> 11, k = idx & 2047;
    const uint32_t u = pack_hl(W[idx] * 1024.0f);
    const int c = k >> 6, kl = k & 63, su = kl >> 2, d = kl & 3;
    img[(size_t)c * 4096 + (e * 16 + (su ^ (e & 7))) * 4 + d] = u;
}

// ---- k1: fused GEMM + softmax + top2 + aux ----
__global__ __launch_bounds__(THREADS, 4)
void router_mfma(const float* __restrict__ x, const uint32_t* __restrict__ wimg,
                 float* __restrict__ out_w, float* __restrict__ out_i,
                 float* __restrict__ g_pi, float* __restrict__ g_cnt) {
    // lx[2][32 rows][16 slots][16B]  = 16 KB   (x packed, swizzled)
    // lw[2][64 rows][16 slots][16B]  = 32 KB   (W packed, swizzled; filled by global_load_lds)
    __shared__ __align__(16) uint32_t sm[2 * 2048 + 2 * 4096];
    __shared__ float apx[8][NE], acn[8][NE];

    uint32_t* lx = sm;            // [2][2048]
    uint32_t* lw = sm + 4096;     // [2][4096]
    float*    ll = (float*)sm;    // logits [32][68], aliased after final barrier

    const int tid  = threadIdx.x;
    const int lane = tid & 63;
    const int wv   = tid >> 6;          // 0..7
    const int rb   = blockIdx.x * BR;

    // staging map (x): thread -> (row, slot)
    const int srow = tid >> 4;          // 0..31
    const int ssu  = tid & 15;          // 0..15, covers kl = ssu*4..+3
    const float* xg = x + (size_t)(rb + srow) * D_MODEL + ssu * 4;
    const int xw_off = (srow * 16 + (ssu ^ (srow & 7))) * 4;

    // compute map: wave -> one 16x16 C-tile
    const int mt = wv >> 2, nt = wv & 3;
    const int arow = mt * 16 + (lane & 15);   // block-local row of A
    const int be   = nt * 16 + (lane & 15);   // expert (col of C)
    const int kq   = lane >> 4;               // k-group 0..3
    const int ap = arow & 7, bp = be & 7;

    f32x4 acc = {0.f, 0.f, 0.f, 0.f};

    // ---- prologue: stage chunk 0 directly, prefetch chunk 1 ----
    {
        const float4 p0 = *(const float4*)xg;
        uint4 w0;
        w0.x = pack_hl(p0.x * 256.f); w0.y = pack_hl(p0.y * 256.f);
        w0.z = pack_hl(p0.z * 256.f); w0.w = pack_hl(p0.w * 256.f);
        *(uint4*)(lx + xw_off) = w0;
        GLD16(wimg + (size_t)tid * 4,         lw + tid * 4);
        GLD16(wimg + (size_t)(tid + 512) * 4, lw + (tid + 512) * 4);
    }
    float4 px = *(const float4*)(xg + BK);
    __syncthreads();

    for (int t = 0; t < NCH; ++t) {
        const int buf = t & 1, nbuf = buf ^ 1;

        if (t + 1 < NCH) {   // issue next W chunk early (overlaps compute)
            const uint32_t* ws = wimg + (size_t)(t + 1) * 4096;
            GLD16(ws + (size_t)tid * 4,         lw + nbuf * 4096 + tid * 4);
            GLD16(ws + (size_t)(tid + 512) * 4, lw + nbuf * 4096 + (tid + 512) * 4);
        }

        const uint32_t* lxb = lx + buf * 2048;
        const uint32_t* lwb = lw + buf * 4096;
        #pragma unroll
        for (int ks = 0; ks < 2; ++ks) {
            const int su0 = ks * 8 + kq * 2;
            U4 a0, a1, b0, b1;
            a0.v = *(const uint4*)(lxb + (arow * 16 + ( su0      ^ ap)) * 4);
            a1.v = *(const uint4*)(lxb + (arow * 16 + ((su0 + 1) ^ ap)) * 4);
            b0.v = *(const uint4*)(lwb + (be   * 16 + ( su0      ^ bp)) * 4);
            b1.v = *(const uint4*)(lwb + (be   * 16 + ((su0 + 1) ^ bp)) * 4);
            F8 ah, al, bh, bl;
            #pragma unroll
            for (int p = 0; p < 2; ++p) {
                ah.u[p]     = __builtin_amdgcn_perm(a0.u[2*p+1], a0.u[2*p], 0x05040100u);
                al.u[p]     = __builtin_amdgcn_perm(a0.u[2*p+1], a0.u[2*p], 0x07060302u);
                ah.u[2 + p] = __builtin_amdgcn_perm(a1.u[2*p+1], a1.u[2*p], 0x05040100u);
                al.u[2 + p] = __builtin_amdgcn_perm(a1.u[2*p+1], a1.u[2*p], 0x07060302u);
                bh.u[p]     = __builtin_amdgcn_perm(b0.u[2*p+1], b0.u[2*p], 0x05040100u);
                bl.u[p]     = __builtin_amdgcn_perm(b0.u[2*p+1], b0.u[2*p], 0x07060302u);
                bh.u[2 + p] = __builtin_amdgcn_perm(b1.u[2*p+1], b1.u[2*p], 0x05040100u);
                bl.u[2 + p] = __builtin_amdgcn_perm(b1.u[2*p+1], b1.u[2*p], 0x07060302u);
            }
            acc = __builtin_amdgcn_mfma_f32_16x16x32_f16(ah.v, bh.v, acc, 0, 0, 0);
            acc = __builtin_amdgcn_mfma_f32_16x16x32_f16(ah.v, bl.v, acc, 0, 0, 0);
            acc = __builtin_amdgcn_mfma_f32_16x16x32_f16(al.v, bh.v, acc, 0, 0, 0);
        }

        if (t + 1 < NCH) {   // convert + write next x chunk, then prefetch t+2
            uint4 wo;
            wo.x = pack_hl(px.x * 256.f); wo.y = pack_hl(px.y * 256.f);
            wo.z = pack_hl(px.z * 256.f); wo.w = pack_hl(px.w * 256.f);
            *(uint4*)(lx + nbuf * 2048 + xw_off) = wo;
            if (t + 2 < NCH) px = *(const float4*)(xg + (size_t)(t + 2) * BK);
        }
        __syncthreads();
    }

    // ---- logits to LDS (undo 2^18 scale exactly) ----
    #pragma unroll
    for (int r = 0; r < 4; ++r) {
        const int row = mt * 16 + kq * 4 + r;     // C/D: col=lane&15, row=(lane>>4)*4+r
        ll[row * 68 + be] = acc[r] * (1.0f / 262144.0f);
    }
    __syncthreads();

    // ---- softmax + top2, wave wv handles rows wv*4..wv*4+3 ----
    float pi_acc = 0.f, cnt_acc = 0.f;
    for (int rr = 0; rr < 4; ++rr) {
        const int row = wv * 4 + rr;
        const float lg = ll[row * 68 + lane];

        float m = lg;
        #pragma unroll
        for (int off = 32; off; off >>= 1) m = fmaxf(m, __shfl_xor(m, off));
        const float e = expf(lg - m);
        float s = e;
        #pragma unroll
        for (int off = 32; off; off >>= 1) s += __shfl_xor(s, off);
        const float score = e / s;

        float v1 = score; int i1 = lane;
        #pragma unroll
        for (int off = 32; off; off >>= 1) {
            const float ov = __shfl_xor(v1, off);
            const int   oi = __shfl_xor(i1, off);
            if (ov > v1 || (ov == v1 && oi < i1)) { v1 = ov; i1 = oi; }
        }
        float v2 = (lane == i1) ? -1.f : score; int i2 = lane;
        #pragma unroll
        for (int off = 32; off; off >>= 1) {
            const float ov = __shfl_xor(v2, off);
            const int   oi = __shfl_xor(i2, off);
            if (ov > v2 || (ov == v2 && oi < i2)) { v2 = ov; i2 = oi; }
        }

        if (lane == 0) {
            const int grow = rb + row;
            const float denom = v1 + v2 + 1e-9f;
            out_w[grow * 2 + 0] = v1 / denom;
            out_w[grow * 2 + 1] = v2 / denom;
            out_i[grow * 2 + 0] = (float)i1;
            out_i[grow * 2 + 1] = (float)i2;
        }
        pi_acc  += score;
        cnt_acc += (float)((lane == i1) + (lane == i2));
    }

    apx[wv][lane] = pi_acc;
    acn[wv][lane] = cnt_acc;
    __syncthreads();

    if (tid < NE) {
        float p = 0.f, c = 0.f;
        #pragma unroll
        for (int w = 0; w < 8; ++w) { p += apx[w][tid]; c += acn[w][tid]; }
        atomicAdd(&g_pi[tid],  p);
        atomicAdd(&g_cnt[tid], c);
    }
}

__global__ void router_finalize(const float* __restrict__ g_pi,
                                const float* __restrict__ g_cnt,
                                float* __restrict__ aux_out) {
    const int lane = threadIdx.x;  // 64
    const float pi = g_pi[lane] * (1.0f / (float)N_ROWS);
    const float fi = g_cnt[lane] * (64.0f / (float)(N_ROWS * 2));
    float v = pi * fi;
    #pragma unroll
    for (int off = 32; off; off >>= 1) v += __shfl_xor(v, off);
    if (lane == 0) aux_out[0] = v * ALPHA;
}

extern "C" void kernel_launch(void* const* d_in, const int* in_sizes, int n_in,
                              void* d_out, int out_size, void* d_ws, size_t ws_size,
                              hipStream_t stream) {
    const float* x = (const float*)d_in[0];
    const float* W = (const float*)d_in[1];

    float* out   = (float*)d_out;
    float* out_w = out;                   // [N,2]
    float* out_i = out + N_ROWS * 2;      // [N,2] as float
    float* aux   = out + N_ROWS * 4;      // [1]

    float*    g_pi  = (float*)d_ws;               // [64]
    float*    g_cnt = g_pi + NE;                  // [64]
    uint32_t* wimg  = (uint32_t*)d_ws + 256;      // [32][4096] = 512 KB packed W image

    hipMemsetAsync(d_ws, 0, 512, stream);

    w_prep<<<dim3(512), dim3(256), 0, stream>>>(W, wimg);
    router_mfma<<<dim3(N_ROWS / BR), dim3(THREADS), 0, stream>>>(
        x, wimg, out_w, out_i, g_pi, g_cnt);
    router_finalize<<<dim3(1), dim3(64), 0, stream>>>(g_pi, g_cnt, aux);
}

// Round 7
// 218.207 us; speedup vs baseline: 1.1426x; 1.0006x over previous
//
#include <hip/hip_runtime.h>
#include <math.h>
#include <stdint.h>

// Router: x[4,4096,2048] f32, W[64,2048] f32
// out f32 concat: topk_weight[16384,2], topk_idx[16384,2] (as float), aux_loss[1]
//
// f16-split MFMA design (3-term: xh*wh + xh*wl + xl*wh):
//   k0 w_prep: W -> two f16 planes (hi, lo), XOR-swizzled for linear global_load_lds
//   k1 router_mfma: fused GEMM (16x16x32 f16 MFMA) + softmax + top2 + aux
//       - counted-vmcnt raw barriers: px prefetch stays in flight across barriers
//   k2 router_finalize: aux scalar
// Scaling: x*256, W*1024 (exact pow2), logits /2^18 in epilogue (exact).

#define D_MODEL 2048
#define NE      64
#define N_ROWS  16384
#define ALPHA   0.01f
#define BR      32
#define BK      64
#define NCH     (D_MODEL / BK)   // 32
#define THREADS 512

typedef _Float16 f16x8 __attribute__((ext_vector_type(8)));
typedef float    f32x4 __attribute__((ext_vector_type(4)));

union U4 { uint32_t u[4]; uint4 v; };
union F8 { uint32_t u[4]; f16x8 v; };

__device__ __forceinline__ uint32_t pack_hl(float xs) {
    _Float16 h = (_Float16)xs;
    float hf = (float)h;
    _Float16 l = (_Float16)(xs - hf);
    union { _Float16 f; uint16_t b; } ch, cl;
    ch.f = h; cl.f = l;
    return (uint32_t)ch.b | ((uint32_t)cl.b << 16);
}

#define GLD16(src, dst) __builtin_amdgcn_global_load_lds( \
    (const __attribute__((address_space(1))) void*)(src), \
    (__attribute__((address_space(3))) void*)(dst), 16, 0, 0)

// counted-vmcnt raw barriers (T4-lite): keep px in flight across the barrier.
#define BAR_KEEP1() { asm volatile("s_waitcnt vmcnt(1) lgkmcnt(0)" ::: "memory"); \
                      __builtin_amdgcn_s_barrier(); \
                      __builtin_amdgcn_sched_barrier(0); }
#define BAR_FULL()  { asm volatile("s_waitcnt vmcnt(0) lgkmcnt(0)" ::: "memory"); \
                      __builtin_amdgcn_s_barrier(); \
                      __builtin_amdgcn_sched_barrier(0); }

// ---- k0: W -> two f16 planes per 64-k chunk, swizzled ----
// chunk c (k = c*64 + kl): plane row e = 8 slots x 16B (8 f16 each), slot ^= (e&7).
// img u32 layout: [c][0..2047] = hi plane, [c][2048..4095] = lo plane.
__global__ __launch_bounds__(256)
void w_prep(const float* __restrict__ W, uint32_t* __restrict__ img) {
    const int idx = blockIdx.x * 256 + threadIdx.x;   // 0..65535
    const int e = idx >> 10, kp = (idx & 1023) * 2;   // even k pair
    const float w0 = W[(size_t)e * D_MODEL + kp]     * 1024.0f;
    const float w1 = W[(size_t)e * D_MODEL + kp + 1] * 1024.0f;
    _Float16 h0 = (_Float16)w0; _Float16 l0 = (_Float16)(w0 - (float)h0);
    _Float16 h1 = (_Float16)w1; _Float16 l1 = (_Float16)(w1 - (float)h1);
    union { _Float16 f[2]; uint32_t u; } ph, pl;
    ph.f[0] = h0; ph.f[1] = h1;
    pl.f[0] = l0; pl.f[1] = l1;
    const int c = kp >> 6, kl = kp & 63;
    const int slot = kl >> 3, uo = (kl & 7) >> 1;
    const int so = (e * 8 + (slot ^ (e & 7))) * 4 + uo;   // u32 index in plane
    uint32_t* base = img + (size_t)c * 4096;
    base[so]        = ph.u;
    base[2048 + so] = pl.u;
}

// ---- k1: fused GEMM + softmax + top2 + aux ----
__global__ __launch_bounds__(THREADS, 4)
void router_mfma(const float* __restrict__ x, const uint32_t* __restrict__ wimg,
                 float* __restrict__ out_w, float* __restrict__ out_i,
                 float* __restrict__ g_pi, float* __restrict__ g_cnt) {
    // lx[2][32 rows][16 slots][16B] = 16 KB  (x packed hi|lo, swizzled)
    // lw[2][hi 8KB + lo 8KB]        = 32 KB  (W planes, filled by global_load_lds)
    __shared__ __align__(16) uint32_t sm[2 * 2048 + 2 * 4096];
    __shared__ float apx[8][NE], acn[8][NE];

    uint32_t* lx = sm;            // [2][2048]
    uint32_t* lw = sm + 4096;     // [2][4096]
    float*    ll = (float*)sm;    // logits [32][68], aliased after final barrier

    const int tid  = threadIdx.x;
    const int lane = tid & 63;
    const int wv   = tid >> 6;          // 0..7
    const int rb   = blockIdx.x * BR;

    // staging map (x): thread -> (row, 16B slot)
    const int srow = tid >> 4;          // 0..31
    const int ssu  = tid & 15;          // 0..15, covers kl = ssu*4..+3
    const float* xg = x + (size_t)(rb + srow) * D_MODEL + ssu * 4;
    const int xw_off = (srow * 16 + (ssu ^ (srow & 7))) * 4;

    // compute map: wave -> one 16x16 C-tile
    const int mt = wv >> 2, nt = wv & 3;
    const int arow = mt * 16 + (lane & 15);   // block-local row of A
    const int be   = nt * 16 + (lane & 15);   // expert (col of C)
    const int kq   = lane >> 4;               // k-group 0..3
    const int ap = arow & 7, bp = be & 7;

    f32x4 acc = {0.f, 0.f, 0.f, 0.f};

    // ---- prologue: stage chunk 0, prefetch px = chunk 1 ----
    {
        const float4 p0 = *(const float4*)xg;
        uint4 w0;
        w0.x = pack_hl(p0.x * 256.f); w0.y = pack_hl(p0.y * 256.f);
        w0.z = pack_hl(p0.z * 256.f); w0.w = pack_hl(p0.w * 256.f);
        *(uint4*)(lx + xw_off) = w0;
        GLD16(wimg + (size_t)tid * 4,         lw + tid * 4);
        GLD16(wimg + (size_t)(tid + 512) * 4, lw + (tid + 512) * 4);
    }
    float4 px = *(const float4*)(xg + BK);
    BAR_KEEP1();   // queue [W0,W0,px1]: wait W, keep px in flight

    for (int t = 0; t < NCH; ++t) {
        const int buf = t & 1, nbuf = buf ^ 1;

        if (t + 1 < NCH) {   // issue next W chunk early
            const uint32_t* ws = wimg + (size_t)(t + 1) * 4096;
            GLD16(ws + (size_t)tid * 4,         lw + nbuf * 4096 + tid * 4);
            GLD16(ws + (size_t)(tid + 512) * 4, lw + nbuf * 4096 + (tid + 512) * 4);
        }

        const uint32_t* lxb = lx + buf * 2048;
        const uint32_t* lwb = lw + buf * 4096;
        #pragma unroll
        for (int ks = 0; ks < 2; ++ks) {
            const int su0 = ks * 8 + kq * 2;   // packed-x 16B slot (4 k each)
            const int sb  = ks * 4 + kq;       // plane 16B slot (8 f16 each)
            U4 a0, a1;
            a0.v = *(const uint4*)(lxb + (arow * 16 + ( su0      ^ ap)) * 4);
            a1.v = *(const uint4*)(lxb + (arow * 16 + ((su0 + 1) ^ ap)) * 4);
            F8 bh, bl;
            bh.v = *(const f16x8*)(lwb +        (be * 8 + (sb ^ bp)) * 4);
            bl.v = *(const f16x8*)(lwb + 2048 + (be * 8 + (sb ^ bp)) * 4);
            F8 ah, al;
            #pragma unroll
            for (int p = 0; p < 2; ++p) {
                ah.u[p]     = __builtin_amdgcn_perm(a0.u[2*p+1], a0.u[2*p], 0x05040100u);
                al.u[p]     = __builtin_amdgcn_perm(a0.u[2*p+1], a0.u[2*p], 0x07060302u);
                ah.u[2 + p] = __builtin_amdgcn_perm(a1.u[2*p+1], a1.u[2*p], 0x05040100u);
                al.u[2 + p] = __builtin_amdgcn_perm(a1.u[2*p+1], a1.u[2*p], 0x07060302u);
            }
            acc = __builtin_amdgcn_mfma_f32_16x16x32_f16(ah.v, bh.v, acc, 0, 0, 0);
            acc = __builtin_amdgcn_mfma_f32_16x16x32_f16(ah.v, bl.v, acc, 0, 0, 0);
            acc = __builtin_amdgcn_mfma_f32_16x16x32_f16(al.v, bh.v, acc, 0, 0, 0);
        }

        if (t + 1 < NCH) {   // convert + write next x chunk, then prefetch t+2
            uint4 wo;
            wo.x = pack_hl(px.x * 256.f); wo.y = pack_hl(px.y * 256.f);
            wo.z = pack_hl(px.z * 256.f); wo.w = pack_hl(px.w * 256.f);
            *(uint4*)(lx + nbuf * 2048 + xw_off) = wo;
            if (t + 2 < NCH) px = *(const float4*)(xg + (size_t)(t + 2) * BK);
        }

        // barrier: W(t+1) (oldest 2 in FIFO) must land for all waves; px(t+2)
        // (newest) stays in flight. Tail: drain fully.
        if (t + 2 < NCH) { BAR_KEEP1(); } else { BAR_FULL(); }
    }

    // ---- logits to LDS (undo 2^18 scale exactly) ----
    #pragma unroll
    for (int r = 0; r < 4; ++r) {
        const int row = mt * 16 + kq * 4 + r;     // C/D: col=lane&15, row=(lane>>4)*4+r
        ll[row * 68 + be] = acc[r] * (1.0f / 262144.0f);
    }
    __syncthreads();

    // ---- softmax + top2, wave wv handles rows wv*4..wv*4+3 ----
    float pi_acc = 0.f, cnt_acc = 0.f;
    for (int rr = 0; rr < 4; ++rr) {
        const int row = wv * 4 + rr;
        const float lg = ll[row * 68 + lane];

        float m = lg;
        #pragma unroll
        for (int off = 32; off; off >>= 1) m = fmaxf(m, __shfl_xor(m, off));
        const float e = expf(lg - m);
        float s = e;
        #pragma unroll
        for (int off = 32; off; off >>= 1) s += __shfl_xor(s, off);
        const float score = e / s;

        float v1 = score; int i1 = lane;
        #pragma unroll
        for (int off = 32; off; off >>= 1) {
            const float ov = __shfl_xor(v1, off);
            const int   oi = __shfl_xor(i1, off);
            if (ov > v1 || (ov == v1 && oi < i1)) { v1 = ov; i1 = oi; }
        }
        float v2 = (lane == i1) ? -1.f : score; int i2 = lane;
        #pragma unroll
        for (int off = 32; off; off >>= 1) {
            const float ov = __shfl_xor(v2, off);
            const int   oi = __shfl_xor(i2, off);
            if (ov > v2 || (ov == v2 && oi < i2)) { v2 = ov; i2 = oi; }
        }

        if (lane == 0) {
            const int grow = rb + row;
            const float denom = v1 + v2 + 1e-9f;
            out_w[grow * 2 + 0] = v1 / denom;
            out_w[grow * 2 + 1] = v2 / denom;
            out_i[grow * 2 + 0] = (float)i1;
            out_i[grow * 2 + 1] = (float)i2;
        }
        pi_acc  += score;
        cnt_acc += (float)((lane == i1) + (lane == i2));
    }

    apx[wv][lane] = pi_acc;
    acn[wv][lane] = cnt_acc;
    __syncthreads();

    if (tid < NE) {
        float p = 0.f, c = 0.f;
        #pragma unroll
        for (int w = 0; w < 8; ++w) { p += apx[w][tid]; c += acn[w][tid]; }
        atomicAdd(&g_pi[tid],  p);
        atomicAdd(&g_cnt[tid], c);
    }
}

__global__ void router_finalize(const float* __restrict__ g_pi,
                                const float* __restrict__ g_cnt,
                                float* __restrict__ aux_out) {
    const int lane = threadIdx.x;  // 64
    const float pi = g_pi[lane] * (1.0f / (float)N_ROWS);
    const float fi = g_cnt[lane] * (64.0f / (float)(N_ROWS * 2));
    float v = pi * fi;
    #pragma unroll
    for (int off = 32; off; off >>= 1) v += __shfl_xor(v, off);
    if (lane == 0) aux_out[0] = v * ALPHA;
}

extern "C" void kernel_launch(void* const* d_in, const int* in_sizes, int n_in,
                              void* d_out, int out_size, void* d_ws, size_t ws_size,
                              hipStream_t stream) {
    const float* x = (const float*)d_in[0];
    const float* W = (const float*)d_in[1];

    float* out   = (float*)d_out;
    float* out_w = out;                   // [N,2]
    float* out_i = out + N_ROWS * 2;      // [N,2] as float
    float* aux   = out + N_ROWS * 4;      // [1]

    float*    g_pi  = (float*)d_ws;               // [64]
    float*    g_cnt = g_pi + NE;                  // [64]
    uint32_t* wimg  = (uint32_t*)d_ws + 256;      // [32][4096] = 512 KB W plane image

    hipMemsetAsync(d_ws, 0, 512, stream);

    w_prep<<<dim3(256), dim3(256), 0, stream>>>(W, wimg);
    router_mfma<<<dim3(N_ROWS / BR), dim3(THREADS), 0, stream>>>(
        x, wimg, out_w, out_i, g_pi, g_cnt);
    router_finalize<<<dim3(1), dim3(64), 0, stream>>>(g_pi, g_cnt, aux);
}